// Round 1
// baseline (832.214 us; speedup 1.0000x reference)
//
#include <hip/hip_runtime.h>
#include <math.h>

// GATv2, 3 layers. N=50000, E=500000, F_IN=128, H=4, D=32 (layers 0/1), HO=6, C=40 (layer 2).
// Strategy: CSR-by-dst (counting sort) -> per-node fused online-softmax aggregation (no float atomics),
// fp32 tiled GEMMs for feature projections, residual mean folded into a small GEMM.

#define LRELU(x) ((x) >= 0.f ? (x) : 0.2f * (x))

// ---------------- CSR build ----------------
__global__ void k_zero(int* __restrict__ cnt, int* __restrict__ fill, int N) {
  int i = blockIdx.x * blockDim.x + threadIdx.x;
  if (i < N) { cnt[i] = 0; fill[i] = 0; }
}

__global__ void k_count(const int* __restrict__ dst, int* __restrict__ cnt, int E) {
  int e = blockIdx.x * blockDim.x + threadIdx.x;
  if (e < E) atomicAdd(&cnt[dst[e]], 1);
}

__global__ void k_scan1(const int* __restrict__ cnt, int* __restrict__ row_ptr,
                        int* __restrict__ bsum, int N) {
  __shared__ int s[256];
  int tid = threadIdx.x;
  int i = blockIdx.x * 256 + tid;
  int v = (i < N) ? cnt[i] : 0;
  s[tid] = v;
  __syncthreads();
  for (int off = 1; off < 256; off <<= 1) {
    int t = (tid >= off) ? s[tid - off] : 0;
    __syncthreads();
    s[tid] += t;
    __syncthreads();
  }
  if (i < N) row_ptr[i] = s[tid] - v;   // block-local exclusive
  if (tid == 255) bsum[blockIdx.x] = s[255];
}

__global__ void k_scan2(int* __restrict__ bsum, int nb) {
  __shared__ int s[256];
  int t = threadIdx.x;
  int v = (t < nb) ? bsum[t] : 0;
  s[t] = v;
  __syncthreads();
  for (int off = 1; off < 256; off <<= 1) {
    int tt = (t >= off) ? s[t - off] : 0;
    __syncthreads();
    s[t] += tt;
    __syncthreads();
  }
  if (t < nb) bsum[t] = s[t] - v;       // exclusive block offsets
}

__global__ void k_scan3(int* __restrict__ row_ptr, const int* __restrict__ bsum, int N, int E) {
  int i = blockIdx.x * blockDim.x + threadIdx.x;
  if (i < N) row_ptr[i] += bsum[i >> 8];
  else if (i == N) row_ptr[N] = E;
}

__global__ void k_scatter(const int* __restrict__ src, const int* __restrict__ dst,
                          const int* __restrict__ row_ptr, int* __restrict__ fill,
                          int* __restrict__ csr_src, int E) {
  int e = blockIdx.x * blockDim.x + threadIdx.x;
  if (e >= E) return;
  int d = dst[e];
  int pos = row_ptr[d] + atomicAdd(&fill[d], 1);
  csr_src[pos] = src[e];
}

// ---------------- Wres2 head-mean fold: wm[k][c] = mean_ho Wres2[k][ho*40+c] ----------------
__global__ void k_wmean(const float* __restrict__ wres2, float* __restrict__ wm) {
  int i = blockIdx.x * blockDim.x + threadIdx.x;   // 128*40
  if (i >= 128 * 40) return;
  int k = i / 40, c = i % 40;
  float s = 0.f;
#pragma unroll
  for (int ho = 0; ho < 6; ++ho) s += wres2[k * 240 + ho * 40 + c];
  wm[i] = s * (1.0f / 6.0f);
}

// ---------------- GEMM: C[N][128] = A[N][128] @ B[128][128] ----------------
__global__ __launch_bounds__(256) void k_gemm128(const float* __restrict__ A,
                                                 const float* __restrict__ B,
                                                 float* __restrict__ C, int N) {
  __shared__ __align__(16) float Bs[16 * 128];
  __shared__ __align__(16) float As[16][128];   // [k][row] transposed chunk
  int tid = threadIdx.x;
  int row0 = blockIdx.x * 128;
  int ty = tid >> 4, tx = tid & 15;
  int r0 = ty * 8, c0 = tx * 8;
  float acc[8][8] = {};
  for (int kk = 0; kk < 128; kk += 16) {
    __syncthreads();
    // B chunk: 16 full rows are contiguous
    for (int i = tid * 4; i < 2048; i += 1024)
      *(float4*)&Bs[i] = *(const float4*)&B[kk * 128 + i];
    // A chunk transposed
    {
      int row = tid >> 1;
      int kc = (tid & 1) * 8;
      int gr = row0 + row;
      float4 v0 = {0, 0, 0, 0}, v1 = {0, 0, 0, 0};
      if (gr < N) {
        v0 = *(const float4*)&A[(size_t)gr * 128 + kk + kc];
        v1 = *(const float4*)&A[(size_t)gr * 128 + kk + kc + 4];
      }
      As[kc + 0][row] = v0.x; As[kc + 1][row] = v0.y;
      As[kc + 2][row] = v0.z; As[kc + 3][row] = v0.w;
      As[kc + 4][row] = v1.x; As[kc + 5][row] = v1.y;
      As[kc + 6][row] = v1.z; As[kc + 7][row] = v1.w;
    }
    __syncthreads();
#pragma unroll
    for (int k = 0; k < 16; ++k) {
      float a[8], b[8];
      *(float4*)&a[0] = *(const float4*)&As[k][r0];
      *(float4*)&a[4] = *(const float4*)&As[k][r0 + 4];
      *(float4*)&b[0] = *(const float4*)&Bs[k * 128 + c0];
      *(float4*)&b[4] = *(const float4*)&Bs[k * 128 + c0 + 4];
#pragma unroll
      for (int i = 0; i < 8; ++i)
#pragma unroll
        for (int j = 0; j < 8; ++j) acc[i][j] += a[i] * b[j];
    }
  }
#pragma unroll
  for (int i = 0; i < 8; ++i) {
    int gr = row0 + r0 + i;
    if (gr < N) {
      *(float4*)&C[(size_t)gr * 128 + c0] = *(float4*)&acc[i][0];
      *(float4*)&C[(size_t)gr * 128 + c0 + 4] = *(float4*)&acc[i][4];
    }
  }
}

// ---------------- GEMM: C[N][240] = A[N][128] @ B[128][240] ----------------
__global__ __launch_bounds__(512) void k_gemm240(const float* __restrict__ A,
                                                 const float* __restrict__ B,
                                                 float* __restrict__ C, int N) {
  __shared__ __align__(16) float Bs[16 * 256];   // cols padded to 256 (pad = 0)
  __shared__ __align__(16) float As[16][128];
  int tid = threadIdx.x;
  int row0 = blockIdx.x * 128;
  int ty = tid >> 5;   // 0..15
  int tx = tid & 31;   // 0..31
  int r0 = ty * 8, c0 = tx * 8;
  float acc[8][8] = {};
  for (int kk = 0; kk < 128; kk += 16) {
    __syncthreads();
    for (int i = tid; i < 16 * 256; i += 512) {
      int k = i >> 8, c = i & 255;
      Bs[i] = (c < 240) ? B[(size_t)(kk + k) * 240 + c] : 0.f;
    }
    {
      int row = tid >> 2;
      int kc = (tid & 3) * 4;
      int gr = row0 + row;
      float4 v = {0, 0, 0, 0};
      if (gr < N) v = *(const float4*)&A[(size_t)gr * 128 + kk + kc];
      As[kc + 0][row] = v.x; As[kc + 1][row] = v.y;
      As[kc + 2][row] = v.z; As[kc + 3][row] = v.w;
    }
    __syncthreads();
#pragma unroll
    for (int k = 0; k < 16; ++k) {
      float a[8], b[8];
      *(float4*)&a[0] = *(const float4*)&As[k][r0];
      *(float4*)&a[4] = *(const float4*)&As[k][r0 + 4];
      *(float4*)&b[0] = *(const float4*)&Bs[k * 256 + c0];
      *(float4*)&b[4] = *(const float4*)&Bs[k * 256 + c0 + 4];
#pragma unroll
      for (int i = 0; i < 8; ++i)
#pragma unroll
        for (int j = 0; j < 8; ++j) acc[i][j] += a[i] * b[j];
    }
  }
  if (c0 < 240) {
#pragma unroll
    for (int i = 0; i < 8; ++i) {
      int gr = row0 + r0 + i;
      if (gr < N) {
        *(float4*)&C[(size_t)gr * 240 + c0] = *(float4*)&acc[i][0];
        *(float4*)&C[(size_t)gr * 240 + c0 + 4] = *(float4*)&acc[i][4];
      }
    }
  }
}

// ---------------- res_mean[N][40] = A[N][128] @ Wm[128][40] ----------------
__global__ __launch_bounds__(256) void k_resmean(const float* __restrict__ A,
                                                 const float* __restrict__ Wm,
                                                 float* __restrict__ out, int N) {
  __shared__ float w[128 * 40];
  for (int i = threadIdx.x; i < 128 * 40; i += 256) w[i] = Wm[i];
  __syncthreads();
  int r = blockIdx.x * 256 + threadIdx.x;
  if (r >= N) return;
  float acc[40] = {};
  for (int k = 0; k < 128; k += 4) {
    float4 hv = *(const float4*)&A[(size_t)r * 128 + k];
#pragma unroll
    for (int j = 0; j < 40; ++j)
      acc[j] += hv.x * w[(k + 0) * 40 + j] + hv.y * w[(k + 1) * 40 + j] +
                hv.z * w[(k + 2) * 40 + j] + hv.w * w[(k + 3) * 40 + j];
  }
#pragma unroll
  for (int j = 0; j < 40; j += 4)
    *(float4*)&out[(size_t)r * 40 + j] = make_float4(acc[j], acc[j + 1], acc[j + 2], acc[j + 3]);
}

// ---------------- Fused edge softmax + aggregate, layers 0/1 (H=4, D=32) ----------------
// One wave per node. lane = h*16 + j holds d = {2j, 2j+1} of head h.
// Dst row held in registers; each edge costs one coalesced 512B src-row gather used
// for BOTH the GATv2 logit (shfl reduce within 16-lane head group) and the weighted sum.
template <bool RES>
__global__ __launch_bounds__(256) void k_agg_fused(const float* __restrict__ feat,
                                                   const float* __restrict__ attn,
                                                   const int* __restrict__ row_ptr,
                                                   const int* __restrict__ csr_src,
                                                   const float* __restrict__ hres,
                                                   float* __restrict__ out, int N) {
  int wid = (blockIdx.x * 256 + threadIdx.x) >> 6;
  if (wid >= N) return;
  int lane = threadIdx.x & 63;
  float2 fd = *(const float2*)&feat[(size_t)wid * 128 + lane * 2];
  float2 av = *(const float2*)&attn[lane * 2];
  int p0 = row_ptr[wid], p1 = row_ptr[wid + 1];
  float m = -INFINITY, sum = 0.f, acc0 = 0.f, acc1 = 0.f;
  for (int p = p0; p < p1; ++p) {
    int s = csr_src[p];
    float2 fs = *(const float2*)&feat[(size_t)s * 128 + lane * 2];
    float x0 = fs.x + fd.x, x1 = fs.y + fd.y;
    x0 = LRELU(x0);
    x1 = LRELU(x1);
    float part = av.x * x0 + av.y * x1;
    part += __shfl_xor(part, 1);
    part += __shfl_xor(part, 2);
    part += __shfl_xor(part, 4);
    part += __shfl_xor(part, 8);   // 16-lane head-group sum -> logit
    float l = part;
    float mn = fmaxf(m, l);
    float sc = __expf(m - mn);   // first iter: exp(-inf)=0
    float pe = __expf(l - mn);
    sum = sum * sc + pe;
    acc0 = acc0 * sc + pe * fs.x;
    acc1 = acc1 * sc + pe * fs.y;
    m = mn;
  }
  float inv = (p1 > p0) ? 1.0f / sum : 0.f;
  float r0 = acc0 * inv, r1 = acc1 * inv;
  if (RES) {
    float2 hv = *(const float2*)&hres[(size_t)wid * 128 + lane * 2];
    r0 += hv.x;
    r1 += hv.y;
  }
  r0 = r0 > 0.f ? r0 : expm1f(r0);   // elu
  r1 = r1 > 0.f ? r1 : expm1f(r1);
  float2 o;
  o.x = r0;
  o.y = r1;
  *(float2*)&out[(size_t)wid * 128 + lane * 2] = o;
}

// ---------------- Fused layer 2 (HO=6, C=40) + head-mean + residual -> d_out ----------------
// One block (6 waves) per node; wave = head, lane < 40 = class channel.
__global__ __launch_bounds__(384) void k_agg2_fused(const float* __restrict__ feat2,
                                                    const float* __restrict__ attn2,
                                                    const int* __restrict__ row_ptr,
                                                    const int* __restrict__ csr_src,
                                                    const float* __restrict__ resm,
                                                    float* __restrict__ out, int N) {
  __shared__ float rs[6 * 40];
  int n = blockIdx.x;
  int wv = threadIdx.x >> 6;   // head 0..5
  int lane = threadIdx.x & 63;
  bool act = lane < 40;
  float fd = act ? feat2[(size_t)n * 240 + wv * 40 + lane] : 0.f;
  float av = act ? attn2[wv * 40 + lane] : 0.f;
  int p0 = row_ptr[n], p1 = row_ptr[n + 1];
  float m = -INFINITY, sum = 0.f, acc = 0.f;
  for (int p = p0; p < p1; ++p) {
    int s = csr_src[p];
    float fs = act ? feat2[(size_t)s * 240 + wv * 40 + lane] : 0.f;
    float x = fs + fd;
    x = LRELU(x);
    float part = av * x;   // lanes >= 40 contribute 0
    part += __shfl_xor(part, 1);
    part += __shfl_xor(part, 2);
    part += __shfl_xor(part, 4);
    part += __shfl_xor(part, 8);
    part += __shfl_xor(part, 16);
    part += __shfl_xor(part, 32);
    float l = part;
    float mn = fmaxf(m, l);
    float sc = __expf(m - mn);
    float pe = __expf(l - mn);
    sum = sum * sc + pe;
    acc = acc * sc + pe * fs;
    m = mn;
  }
  float r = (p1 > p0) ? acc / sum : 0.f;
  if (act) rs[wv * 40 + lane] = r;
  __syncthreads();
  if (threadIdx.x < 40) {
    int c = threadIdx.x;
    float v = (rs[c] + rs[40 + c] + rs[80 + c] + rs[120 + c] + rs[160 + c] + rs[200 + c]) *
                  (1.0f / 6.0f) +
              resm[(size_t)n * 40 + c];
    out[(size_t)n * 40 + c] = v;
  }
}

// ---------------- host ----------------
extern "C" void kernel_launch(void* const* d_in, const int* in_sizes, int n_in,
                              void* d_out, int out_size, void* d_ws, size_t ws_size,
                              hipStream_t stream) {
  const float* inputs = (const float*)d_in[0];
  const int* src = (const int*)d_in[1];
  const int* dst = (const int*)d_in[2];
  const float* W0 = (const float*)d_in[3];
  const float* attn0 = (const float*)d_in[4];
  const float* W1 = (const float*)d_in[5];
  const float* attn1 = (const float*)d_in[6];
  const float* W2 = (const float*)d_in[7];
  const float* attn2 = (const float*)d_in[8];
  const float* Wres2 = (const float*)d_in[9];
  const int N = in_sizes[0] / 128;
  const int E = in_sizes[1];

  char* base = (char*)d_ws;
  size_t off = 0;
  auto alloc = [&](size_t bytes) -> void* {
    void* q = base + off;
    off += (bytes + 255) & ~(size_t)255;
    return q;
  };
  int* cnt = (int*)alloc((size_t)N * 4);
  int* fill = (int*)alloc((size_t)N * 4);
  int* row_ptr = (int*)alloc((size_t)(N + 1) * 4);
  int* bsum = (int*)alloc(1024 * 4);          // N <= 65536 assumed (N=50000)
  int* csr_src = (int*)alloc((size_t)E * 4);
  float* F = (float*)alloc((size_t)N * 240 * 4);    // feat0/feat1 (N x 128) and feat2 (N x 240)
  float* h1 = (float*)alloc((size_t)N * 128 * 4);
  float* h2 = (float*)alloc((size_t)N * 128 * 4);
  float* resm = (float*)alloc((size_t)N * 40 * 4);
  float* wm = (float*)alloc(128 * 40 * 4);
  (void)ws_size;  // ~110 MB used

  const int nb1 = (N + 255) / 256;

  hipLaunchKernelGGL(k_zero, dim3((N + 255) / 256), dim3(256), 0, stream, cnt, fill, N);
  hipLaunchKernelGGL(k_count, dim3((E + 255) / 256), dim3(256), 0, stream, dst, cnt, E);
  hipLaunchKernelGGL(k_scan1, dim3(nb1), dim3(256), 0, stream, cnt, row_ptr, bsum, N);
  hipLaunchKernelGGL(k_scan2, dim3(1), dim3(256), 0, stream, bsum, nb1);
  hipLaunchKernelGGL(k_scan3, dim3((N + 256) / 256), dim3(256), 0, stream, row_ptr, bsum, N, E);
  hipLaunchKernelGGL(k_scatter, dim3((E + 255) / 256), dim3(256), 0, stream, src, dst, row_ptr,
                     fill, csr_src, E);
  hipLaunchKernelGGL(k_wmean, dim3((128 * 40 + 255) / 256), dim3(256), 0, stream, Wres2, wm);

  // layer 0
  hipLaunchKernelGGL(k_gemm128, dim3((N + 127) / 128), dim3(256), 0, stream, inputs, W0, F, N);
  hipLaunchKernelGGL((k_agg_fused<false>), dim3((N + 3) / 4), dim3(256), 0, stream, F, attn0,
                     row_ptr, csr_src, (const float*)nullptr, h1, N);
  // layer 1
  hipLaunchKernelGGL(k_gemm128, dim3((N + 127) / 128), dim3(256), 0, stream, h1, W1, F, N);
  hipLaunchKernelGGL((k_agg_fused<true>), dim3((N + 3) / 4), dim3(256), 0, stream, F, attn1,
                     row_ptr, csr_src, h1, h2, N);
  // layer 2
  hipLaunchKernelGGL(k_gemm240, dim3((N + 127) / 128), dim3(512), 0, stream, h2, W2, F, N);
  hipLaunchKernelGGL(k_resmean, dim3((N + 255) / 256), dim3(256), 0, stream, h2, wm, resm, N);
  hipLaunchKernelGGL(k_agg2_fused, dim3(N), dim3(384), 0, stream, F, attn2, row_ptr, csr_src,
                     resm, (float*)d_out, N);
}

// Round 2
// 551.055 us; speedup vs baseline: 1.5102x; 1.5102x over previous
//
#include <hip/hip_runtime.h>
#include <math.h>

// GATv2, 3 layers. N=50000, E=500000, F_IN=128, H=4, D=32 (layers 0/1), HO=6, C=40 (layer 2).
// CSR-by-dst -> per-node fused online-softmax aggregation (no float atomics),
// fp32 tiled GEMMs for projections, residual head-mean folded into a small GEMM.
// Round 2: agg kernels restructured for latency: one-wave-per-node everywhere,
// float4 gathers, 2 concurrent online-softmax streams (register or half-wave).

#define LRELU(x) ((x) >= 0.f ? (x) : 0.2f * (x))

// ---------------- CSR build ----------------
__global__ void k_zero(int* __restrict__ cnt, int* __restrict__ fill, int N) {
  int i = blockIdx.x * blockDim.x + threadIdx.x;
  if (i < N) { cnt[i] = 0; fill[i] = 0; }
}

__global__ void k_count(const int* __restrict__ dst, int* __restrict__ cnt, int E) {
  int e = blockIdx.x * blockDim.x + threadIdx.x;
  if (e < E) atomicAdd(&cnt[dst[e]], 1);
}

__global__ void k_scan1(const int* __restrict__ cnt, int* __restrict__ row_ptr,
                        int* __restrict__ bsum, int N) {
  __shared__ int s[256];
  int tid = threadIdx.x;
  int i = blockIdx.x * 256 + tid;
  int v = (i < N) ? cnt[i] : 0;
  s[tid] = v;
  __syncthreads();
  for (int off = 1; off < 256; off <<= 1) {
    int t = (tid >= off) ? s[tid - off] : 0;
    __syncthreads();
    s[tid] += t;
    __syncthreads();
  }
  if (i < N) row_ptr[i] = s[tid] - v;
  if (tid == 255) bsum[blockIdx.x] = s[255];
}

__global__ void k_scan2(int* __restrict__ bsum, int nb) {
  __shared__ int s[256];
  int t = threadIdx.x;
  int v = (t < nb) ? bsum[t] : 0;
  s[t] = v;
  __syncthreads();
  for (int off = 1; off < 256; off <<= 1) {
    int tt = (t >= off) ? s[t - off] : 0;
    __syncthreads();
    s[t] += tt;
    __syncthreads();
  }
  if (t < nb) bsum[t] = s[t] - v;
}

__global__ void k_scan3(int* __restrict__ row_ptr, const int* __restrict__ bsum, int N, int E) {
  int i = blockIdx.x * blockDim.x + threadIdx.x;
  if (i < N) row_ptr[i] += bsum[i >> 8];
  else if (i == N) row_ptr[N] = E;
}

__global__ void k_scatter(const int* __restrict__ src, const int* __restrict__ dst,
                          const int* __restrict__ row_ptr, int* __restrict__ fill,
                          int* __restrict__ csr_src, int E) {
  int e = blockIdx.x * blockDim.x + threadIdx.x;
  if (e >= E) return;
  int d = dst[e];
  int pos = row_ptr[d] + atomicAdd(&fill[d], 1);
  csr_src[pos] = src[e];
}

// ---------------- Wres2 head-mean fold ----------------
__global__ void k_wmean(const float* __restrict__ wres2, float* __restrict__ wm) {
  int i = blockIdx.x * blockDim.x + threadIdx.x;
  if (i >= 128 * 40) return;
  int k = i / 40, c = i % 40;
  float s = 0.f;
#pragma unroll
  for (int ho = 0; ho < 6; ++ho) s += wres2[k * 240 + ho * 40 + c];
  wm[i] = s * (1.0f / 6.0f);
}

// ---------------- GEMM: C[N][128] = A[N][128] @ B[128][128] ----------------
__global__ __launch_bounds__(256) void k_gemm128(const float* __restrict__ A,
                                                 const float* __restrict__ B,
                                                 float* __restrict__ C, int N) {
  __shared__ __align__(16) float Bs[16 * 128];
  __shared__ __align__(16) float As[16][128];
  int tid = threadIdx.x;
  int row0 = blockIdx.x * 128;
  int ty = tid >> 4, tx = tid & 15;
  int r0 = ty * 8, c0 = tx * 8;
  float acc[8][8] = {};
  for (int kk = 0; kk < 128; kk += 16) {
    __syncthreads();
    for (int i = tid * 4; i < 2048; i += 1024)
      *(float4*)&Bs[i] = *(const float4*)&B[kk * 128 + i];
    {
      int row = tid >> 1;
      int kc = (tid & 1) * 8;
      int gr = row0 + row;
      float4 v0 = {0, 0, 0, 0}, v1 = {0, 0, 0, 0};
      if (gr < N) {
        v0 = *(const float4*)&A[(size_t)gr * 128 + kk + kc];
        v1 = *(const float4*)&A[(size_t)gr * 128 + kk + kc + 4];
      }
      As[kc + 0][row] = v0.x; As[kc + 1][row] = v0.y;
      As[kc + 2][row] = v0.z; As[kc + 3][row] = v0.w;
      As[kc + 4][row] = v1.x; As[kc + 5][row] = v1.y;
      As[kc + 6][row] = v1.z; As[kc + 7][row] = v1.w;
    }
    __syncthreads();
#pragma unroll
    for (int k = 0; k < 16; ++k) {
      float a[8], b[8];
      *(float4*)&a[0] = *(const float4*)&As[k][r0];
      *(float4*)&a[4] = *(const float4*)&As[k][r0 + 4];
      *(float4*)&b[0] = *(const float4*)&Bs[k * 128 + c0];
      *(float4*)&b[4] = *(const float4*)&Bs[k * 128 + c0 + 4];
#pragma unroll
      for (int i = 0; i < 8; ++i)
#pragma unroll
        for (int j = 0; j < 8; ++j) acc[i][j] += a[i] * b[j];
    }
  }
#pragma unroll
  for (int i = 0; i < 8; ++i) {
    int gr = row0 + r0 + i;
    if (gr < N) {
      *(float4*)&C[(size_t)gr * 128 + c0] = *(float4*)&acc[i][0];
      *(float4*)&C[(size_t)gr * 128 + c0 + 4] = *(float4*)&acc[i][4];
    }
  }
}

// ---------------- GEMM: C[N][240] = A[N][128] @ B[128][240] ----------------
__global__ __launch_bounds__(512) void k_gemm240(const float* __restrict__ A,
                                                 const float* __restrict__ B,
                                                 float* __restrict__ C, int N) {
  __shared__ __align__(16) float Bs[16 * 256];
  __shared__ __align__(16) float As[16][128];
  int tid = threadIdx.x;
  int row0 = blockIdx.x * 128;
  int ty = tid >> 5;
  int tx = tid & 31;
  int r0 = ty * 8, c0 = tx * 8;
  float acc[8][8] = {};
  for (int kk = 0; kk < 128; kk += 16) {
    __syncthreads();
    for (int i = tid; i < 16 * 256; i += 512) {
      int k = i >> 8, c = i & 255;
      Bs[i] = (c < 240) ? B[(size_t)(kk + k) * 240 + c] : 0.f;
    }
    {
      int row = tid >> 2;
      int kc = (tid & 3) * 4;
      int gr = row0 + row;
      float4 v = {0, 0, 0, 0};
      if (gr < N) v = *(const float4*)&A[(size_t)gr * 128 + kk + kc];
      As[kc + 0][row] = v.x; As[kc + 1][row] = v.y;
      As[kc + 2][row] = v.z; As[kc + 3][row] = v.w;
    }
    __syncthreads();
#pragma unroll
    for (int k = 0; k < 16; ++k) {
      float a[8], b[8];
      *(float4*)&a[0] = *(const float4*)&As[k][r0];
      *(float4*)&a[4] = *(const float4*)&As[k][r0 + 4];
      *(float4*)&b[0] = *(const float4*)&Bs[k * 256 + c0];
      *(float4*)&b[4] = *(const float4*)&Bs[k * 256 + c0 + 4];
#pragma unroll
      for (int i = 0; i < 8; ++i)
#pragma unroll
        for (int j = 0; j < 8; ++j) acc[i][j] += a[i] * b[j];
    }
  }
  if (c0 < 240) {
#pragma unroll
    for (int i = 0; i < 8; ++i) {
      int gr = row0 + r0 + i;
      if (gr < N) {
        *(float4*)&C[(size_t)gr * 240 + c0] = *(float4*)&acc[i][0];
        *(float4*)&C[(size_t)gr * 240 + c0 + 4] = *(float4*)&acc[i][4];
      }
    }
  }
}

// ---------------- res_mean[N][40] = A[N][128] @ Wm[128][40] ----------------
__global__ __launch_bounds__(256) void k_resmean(const float* __restrict__ A,
                                                 const float* __restrict__ Wm,
                                                 float* __restrict__ out, int N) {
  __shared__ float w[128 * 40];
  for (int i = threadIdx.x; i < 128 * 40; i += 256) w[i] = Wm[i];
  __syncthreads();
  int r = blockIdx.x * 256 + threadIdx.x;
  if (r >= N) return;
  float acc[40] = {};
  for (int k = 0; k < 128; k += 4) {
    float4 hv = *(const float4*)&A[(size_t)r * 128 + k];
#pragma unroll
    for (int j = 0; j < 40; ++j)
      acc[j] += hv.x * w[(k + 0) * 40 + j] + hv.y * w[(k + 1) * 40 + j] +
                hv.z * w[(k + 2) * 40 + j] + hv.w * w[(k + 3) * 40 + j];
  }
#pragma unroll
  for (int j = 0; j < 40; j += 4)
    *(float4*)&out[(size_t)r * 40 + j] = make_float4(acc[j], acc[j + 1], acc[j + 2], acc[j + 3]);
}

// ---------------- Fused edge softmax + aggregate, layers 0/1 (H=4, D=32) ----------------
// One wave per node. Half-wave per edge: lanes 0-31 take even edges, 32-63 odd edges.
// Lane (l&31) holds float4 at row offset (l&31)*4; head = (l&31)>>3 (8 lanes/head).
// Logit reduce = 3 shfl_xor within 8-lane groups; two online-softmax streams merge at end.
template <bool RES>
__global__ __launch_bounds__(256) void k_agg_fused(const float* __restrict__ feat,
                                                   const float* __restrict__ attn,
                                                   const int* __restrict__ row_ptr,
                                                   const int* __restrict__ csr_src,
                                                   const float* __restrict__ hres,
                                                   float* __restrict__ out, int N) {
  int wid = (blockIdx.x * 256 + threadIdx.x) >> 6;
  bool nok = wid < N;
  int n = nok ? wid : (N - 1);
  int lane = threadIdx.x & 63;
  int half = lane >> 5;
  int c = (lane & 31) * 4;
  float4 fd = *(const float4*)&feat[(size_t)n * 128 + c];
  float4 av = *(const float4*)&attn[c];
  int p0 = row_ptr[n], p1 = row_ptr[n + 1];
  float m = -1e30f, s = 0.f;
  float4 acc = {0.f, 0.f, 0.f, 0.f};
  for (int p = p0; p < p1; p += 2) {
    int pp = p + half;
    bool v = pp < p1;
    int si = csr_src[v ? pp : p];
    float4 fs = *(const float4*)&feat[(size_t)si * 128 + c];
    float x0 = LRELU(fs.x + fd.x), x1 = LRELU(fs.y + fd.y);
    float x2 = LRELU(fs.z + fd.z), x3 = LRELU(fs.w + fd.w);
    float x = av.x * x0 + av.y * x1 + av.z * x2 + av.w * x3;
    x += __shfl_xor(x, 1);
    x += __shfl_xor(x, 2);
    x += __shfl_xor(x, 4);     // 8-lane head group: all lanes hold the logit
    float mn = fmaxf(m, x);
    float sc = __expf(m - mn);          // m=-1e30 -> 0, no NaN
    float pe = v ? __expf(x - mn) : 0.f;
    s = s * sc + pe;
    acc.x = acc.x * sc + pe * fs.x;
    acc.y = acc.y * sc + pe * fs.y;
    acc.z = acc.z * sc + pe * fs.z;
    acc.w = acc.w * sc + pe * fs.w;
    m = mn;
  }
  // merge the two half-wave streams
  float m2 = __shfl_xor(m, 32);
  float s2 = __shfl_xor(s, 32);
  float4 a2;
  a2.x = __shfl_xor(acc.x, 32);
  a2.y = __shfl_xor(acc.y, 32);
  a2.z = __shfl_xor(acc.z, 32);
  a2.w = __shfl_xor(acc.w, 32);
  float mT = fmaxf(m, m2);
  float f1 = __expf(m - mT), f2 = __expf(m2 - mT);
  float ssum = s * f1 + s2 * f2;
  float inv = (p1 > p0) ? 1.0f / ssum : 0.f;
  float4 r;
  r.x = (acc.x * f1 + a2.x * f2) * inv;
  r.y = (acc.y * f1 + a2.y * f2) * inv;
  r.z = (acc.z * f1 + a2.z * f2) * inv;
  r.w = (acc.w * f1 + a2.w * f2) * inv;
  if (RES) {
    float4 hv = *(const float4*)&hres[(size_t)n * 128 + c];
    r.x += hv.x; r.y += hv.y; r.z += hv.z; r.w += hv.w;
  }
  r.x = r.x > 0.f ? r.x : expm1f(r.x);
  r.y = r.y > 0.f ? r.y : expm1f(r.y);
  r.z = r.z > 0.f ? r.z : expm1f(r.z);
  r.w = r.w > 0.f ? r.w : expm1f(r.w);
  if (half == 0 && nok) *(float4*)&out[(size_t)n * 128 + c] = r;
}

// ---------------- Fused layer 2 (HO=6, C=40) + head-mean + residual -> d_out ----------------
// ONE wave per node. lane = ho*10 + t (60 active); lane holds float4 at ho*40 + t*4.
// One 960B gather per edge; 10-lane segmented reduce (4 shfl + bcast).
// Two register online-softmax streams (even/odd edges) merged at end.
__global__ __launch_bounds__(256) void k_agg2_fused(const float* __restrict__ feat2,
                                                    const float* __restrict__ attn2,
                                                    const int* __restrict__ row_ptr,
                                                    const int* __restrict__ csr_src,
                                                    const float* __restrict__ resm,
                                                    float* __restrict__ out, int N) {
  __shared__ float rs[4][240];
  int w = threadIdx.x >> 6;
  int wid = blockIdx.x * 4 + w;
  bool nok = wid < N;
  int n = nok ? wid : (N - 1);
  int lane = threadIdx.x & 63;
  bool act = lane < 60;
  int ho = lane / 10, t = lane % 10;
  int g0 = ho * 10;
  int fo = act ? (ho * 40 + t * 4) : 0;
  float4 zero = {0.f, 0.f, 0.f, 0.f};
  float4 fd = act ? *(const float4*)&feat2[(size_t)n * 240 + fo] : zero;
  float4 av = act ? *(const float4*)&attn2[fo] : zero;
  int p0 = row_ptr[n], p1 = row_ptr[n + 1];
  float mA = -1e30f, sA = 0.f, mB = -1e30f, sB = 0.f;
  float4 aA = zero, aB = zero;
  for (int p = p0; p < p1; p += 2) {
    int iA = csr_src[p];
    bool vB = (p + 1) < p1;
    int iB = vB ? csr_src[p + 1] : iA;
    float4 fA = *(const float4*)&feat2[(size_t)iA * 240 + fo];
    float4 fB = *(const float4*)&feat2[(size_t)iB * 240 + fo];
    float xA = av.x * LRELU(fA.x + fd.x) + av.y * LRELU(fA.y + fd.y) +
               av.z * LRELU(fA.z + fd.z) + av.w * LRELU(fA.w + fd.w);
    float xB = av.x * LRELU(fB.x + fd.x) + av.y * LRELU(fB.y + fd.y) +
               av.z * LRELU(fB.z + fd.z) + av.w * LRELU(fB.w + fd.w);
    // segmented reduce over 10 lanes (t=0..9), interleaved for the two streams
    float aAx = xA + __shfl(xA, lane + 5);
    float aBx = xB + __shfl(xB, lane + 5);
    float bAx = aAx + __shfl(aAx, lane + 1);
    float bBx = aBx + __shfl(aBx, lane + 1);
    float cAx = bAx + __shfl(bAx, lane + 2);
    float cBx = bBx + __shfl(bBx, lane + 2);
    float SA = cAx + __shfl(aAx, lane + 4);   // valid at t==0
    float SB = cBx + __shfl(aBx, lane + 4);
    float lA = __shfl(SA, g0);
    float lB = __shfl(SB, g0);
    // online update, stream A
    float mnA = fmaxf(mA, lA);
    float scA = __expf(mA - mnA);
    float peA = __expf(lA - mnA);
    sA = sA * scA + peA;
    aA.x = aA.x * scA + peA * fA.x;
    aA.y = aA.y * scA + peA * fA.y;
    aA.z = aA.z * scA + peA * fA.z;
    aA.w = aA.w * scA + peA * fA.w;
    mA = mnA;
    // stream B
    float mnB = fmaxf(mB, lB);
    float scB = __expf(mB - mnB);
    float peB = vB ? __expf(lB - mnB) : 0.f;
    sB = sB * scB + peB;
    aB.x = aB.x * scB + peB * fB.x;
    aB.y = aB.y * scB + peB * fB.y;
    aB.z = aB.z * scB + peB * fB.z;
    aB.w = aB.w * scB + peB * fB.w;
    mB = mnB;
  }
  // merge streams
  float mT = fmaxf(mA, mB);
  float f1 = __expf(mA - mT), f2 = __expf(mB - mT);
  float ssum = sA * f1 + sB * f2;
  float inv = (p1 > p0) ? 1.0f / ssum : 0.f;
  float4 r;
  r.x = (aA.x * f1 + aB.x * f2) * inv;
  r.y = (aA.y * f1 + aB.y * f2) * inv;
  r.z = (aA.z * f1 + aB.z * f2) * inv;
  r.w = (aA.w * f1 + aB.w * f2) * inv;
  if (act) *(float4*)&rs[w][fo] = r;
  __syncthreads();
  if (lane < 10 && nok) {
#pragma unroll
    for (int k = 0; k < 4; ++k) {
      int cc = t * 4 + k;
      float v = (rs[w][cc] + rs[w][40 + cc] + rs[w][80 + cc] + rs[w][120 + cc] +
                 rs[w][160 + cc] + rs[w][200 + cc]) * (1.0f / 6.0f) +
                resm[(size_t)n * 40 + cc];
      out[(size_t)n * 40 + cc] = v;
    }
  }
}

// ---------------- host ----------------
extern "C" void kernel_launch(void* const* d_in, const int* in_sizes, int n_in,
                              void* d_out, int out_size, void* d_ws, size_t ws_size,
                              hipStream_t stream) {
  const float* inputs = (const float*)d_in[0];
  const int* src = (const int*)d_in[1];
  const int* dst = (const int*)d_in[2];
  const float* W0 = (const float*)d_in[3];
  const float* attn0 = (const float*)d_in[4];
  const float* W1 = (const float*)d_in[5];
  const float* attn1 = (const float*)d_in[6];
  const float* W2 = (const float*)d_in[7];
  const float* attn2 = (const float*)d_in[8];
  const float* Wres2 = (const float*)d_in[9];
  const int N = in_sizes[0] / 128;
  const int E = in_sizes[1];

  char* base = (char*)d_ws;
  size_t off = 0;
  auto alloc = [&](size_t bytes) -> void* {
    void* q = base + off;
    off += (bytes + 255) & ~(size_t)255;
    return q;
  };
  int* cnt = (int*)alloc((size_t)N * 4);
  int* fill = (int*)alloc((size_t)N * 4);
  int* row_ptr = (int*)alloc((size_t)(N + 1) * 4);
  int* bsum = (int*)alloc(1024 * 4);
  int* csr_src = (int*)alloc((size_t)E * 4);
  float* F = (float*)alloc((size_t)N * 240 * 4);
  float* h1 = (float*)alloc((size_t)N * 128 * 4);
  float* h2 = (float*)alloc((size_t)N * 128 * 4);
  float* resm = (float*)alloc((size_t)N * 40 * 4);
  float* wm = (float*)alloc(128 * 40 * 4);
  (void)ws_size;

  const int nb1 = (N + 255) / 256;

  hipLaunchKernelGGL(k_zero, dim3((N + 255) / 256), dim3(256), 0, stream, cnt, fill, N);
  hipLaunchKernelGGL(k_count, dim3((E + 255) / 256), dim3(256), 0, stream, dst, cnt, E);
  hipLaunchKernelGGL(k_scan1, dim3(nb1), dim3(256), 0, stream, cnt, row_ptr, bsum, N);
  hipLaunchKernelGGL(k_scan2, dim3(1), dim3(256), 0, stream, bsum, nb1);
  hipLaunchKernelGGL(k_scan3, dim3((N + 256) / 256), dim3(256), 0, stream, row_ptr, bsum, N, E);
  hipLaunchKernelGGL(k_scatter, dim3((E + 255) / 256), dim3(256), 0, stream, src, dst, row_ptr,
                     fill, csr_src, E);
  hipLaunchKernelGGL(k_wmean, dim3((128 * 40 + 255) / 256), dim3(256), 0, stream, Wres2, wm);

  // layer 0
  hipLaunchKernelGGL(k_gemm128, dim3((N + 127) / 128), dim3(256), 0, stream, inputs, W0, F, N);
  hipLaunchKernelGGL((k_agg_fused<false>), dim3((N + 3) / 4), dim3(256), 0, stream, F, attn0,
                     row_ptr, csr_src, (const float*)nullptr, h1, N);
  // layer 1
  hipLaunchKernelGGL(k_gemm128, dim3((N + 127) / 128), dim3(256), 0, stream, h1, W1, F, N);
  hipLaunchKernelGGL((k_agg_fused<true>), dim3((N + 3) / 4), dim3(256), 0, stream, F, attn1,
                     row_ptr, csr_src, h1, h2, N);
  // layer 2
  hipLaunchKernelGGL(k_gemm240, dim3((N + 127) / 128), dim3(512), 0, stream, h2, W2, F, N);
  hipLaunchKernelGGL(k_resmean, dim3((N + 255) / 256), dim3(256), 0, stream, h2, wm, resm, N);
  hipLaunchKernelGGL(k_agg2_fused, dim3((N + 3) / 4), dim3(256), 0, stream, F, attn2, row_ptr,
                     csr_src, resm, (float*)d_out, N);
}